// Round 10
// baseline (1266.214 us; speedup 1.0000x reference)
//
#include <hip/hip_runtime.h>
#include <hip/hip_bf16.h>

// SMPL-X LBS forward. B=512, V=10475, J=55. f32 in/out; fp16 MFMA internally.
// SINGLE persistent kernel (grid 768 x 256, co-resident by construction:
// LDS 34048 -> 4 blk/CU, launch_bounds(256,3) -> regs<=170 -> >=3 blk/CU).
// Manual grid barriers (device-scope atomics + threadfence) between phases:
//   ph1 prep : s_dirs | y_offset | lwT packed | jreg   (453 units)
//   ph2 batch: Rodrigues -> PFH packed; chain -> AH    (512 units)
//   ph3 pose : pd^T (split-K LDS stage) x PFH -> VPH2  (984 units: 492 x 2)
//   ph4 lbs  : AH x lwT; VPH2 slice in LDS; LDS-staged monotonic out stores
//              (10496 units, grid-stride)

typedef _Float16 f16;
typedef f16  f16x8 __attribute__((ext_vector_type(8)));
typedef f16  f16x4 __attribute__((ext_vector_type(4)));
typedef float f32x4 __attribute__((ext_vector_type(4)));

#define VN    10475
#define JN    55
#define BN    512
#define VC3   31425
#define NPAD  31488          // 492*64
#define VPADV 10496

// f32 ws region (float offsets):
#define SD_F  0              // s_dirs [VC3]
#define JS_F  31425          // [165]
#define JE_F  31590          // [1650]
#define Y_F   33240
// byte offsets in ws:
#define BAR_BYTE  (150*1024)           // grid-barrier cnt/gen (8 B, memset 0)
#define PFH_BYTE  (160*1024)           // f16 packed [32][16][64][8]
#define AH_BYTE   (768*1024)           // f16 packed [512][2][64][8]
#define VPH_BYTE  (2*1024*1024)        // f16 [512][31488]
#define LWT_BYTE  (34*1024*1024)       // f16 packed [656][2][64][8]

#define NB_SD   123
#define NB_LWT  164
#define NB_JREG 165
#define NB_PREP 453
#define NB_POSE 984                    // 492 col-tiles x 2 batch-halves
#define NB_LBS  10496                  // 164 v-tiles x 64 b-groups
#define GRID    768

#define BTS2 264                       // pose stage row stride (halves)
#define SMEM_BYTES (64*BTS2*2 + 256)   // 34048: pose stage + SDl (max phase)

// ---------------- grid barrier ----------------
__device__ inline void gsync(unsigned* cnt, unsigned* gen, unsigned nb, int t)
{
    __syncthreads();
    if (t == 0) {
        __threadfence();   // agent release: L2 writeback (cross-XCD visibility)
        unsigned g = __hip_atomic_load(gen, __ATOMIC_RELAXED, __HIP_MEMORY_SCOPE_AGENT);
        if (__hip_atomic_fetch_add(cnt, 1u, __ATOMIC_ACQ_REL, __HIP_MEMORY_SCOPE_AGENT) == nb - 1u) {
            __hip_atomic_store(cnt, 0u, __ATOMIC_RELAXED, __HIP_MEMORY_SCOPE_AGENT);
            __hip_atomic_fetch_add(gen, 1u, __ATOMIC_RELEASE, __HIP_MEMORY_SCOPE_AGENT);
        } else {
            while (__hip_atomic_load(gen, __ATOMIC_ACQUIRE, __HIP_MEMORY_SCOPE_AGENT) == g)
                __builtin_amdgcn_s_sleep(8);
        }
        __threadfence();   // agent acquire: invalidate stale lines
    }
    __syncthreads();
}

// ---------------- phase 1: prep ----------------
__device__ void ph_prep(int bb, int tid, char* SMEM,
    const float* __restrict__ vt, const float* __restrict__ shapedirs,
    const float* __restrict__ shape, const float* __restrict__ lw,
    const float* __restrict__ jr, const float* __restrict__ exprdirs,
    float* __restrict__ ws, f16* __restrict__ lwT)
{
    float* red = (float*)SMEM;
    if (bb < NB_SD) {
        int i = bb * 256 + tid;
        if (i < VC3) {
            float acc = vt[i];
            const float* sd = shapedirs + (size_t)i * 10;
            #pragma unroll
            for (int s = 0; s < 10; ++s) acc += shape[s] * sd[s];
            ws[SD_F + i] = acc;
        }
    } else if (bb == NB_SD) {
        float m = 3.0e38f;
        for (int v = tid; v < VN; v += 256) m = fminf(m, vt[v*3 + 1]);
        red[tid] = m;
        __syncthreads();
        for (int s = 128; s > 0; s >>= 1) {
            if (tid < s) red[tid] = fminf(red[tid], red[tid + s]);
            __syncthreads();
        }
        if (tid == 0) ws[Y_F] = -red[0];
        __syncthreads();
    } else if (bb < NB_SD + 1 + NB_LWT) {
        int bx = bb - (NB_SD + 1);
        int v  = bx * 64 + (tid >> 2);
        int jg = (tid & 3) * 16;
        f16 tmp[16];
        #pragma unroll
        for (int jj = 0; jj < 16; ++jj) {
            int j = jg + jj;
            tmp[jj] = (f16)((v < VN && j < JN) ? lw[(size_t)v*JN + j] : 0.f);
        }
        int vtile = v >> 4, lv = v & 15;
        int ks = jg >> 5, q0 = (jg >> 3) & 3;
        *(f16x8*)&lwT[(size_t)vtile*1024 + ks*512 + (q0*16 + lv)*8]     = *(f16x8*)&tmp[0];
        *(f16x8*)&lwT[(size_t)vtile*1024 + ks*512 + ((q0+1)*16 + lv)*8] = *(f16x8*)&tmp[8];
    } else {
        int jb = bb - (NB_SD + 1 + NB_LWT);
        int j = jb / 3, c = jb % 3;
        float acc[11];
        #pragma unroll
        for (int i = 0; i < 11; ++i) acc[i] = 0.f;
        for (int v = tid; v < VN; v += 256) {
            float w = jr[(size_t)j * VN + v];
            float sv = vt[v*3 + c];
            const float* sd = shapedirs + (size_t)(v*3 + c) * 10;
            #pragma unroll
            for (int s = 0; s < 10; ++s) sv += shape[s] * sd[s];
            acc[10] += w * sv;
            const float* edp = exprdirs + (size_t)(v*3 + c) * 10;
            #pragma unroll
            for (int e = 0; e < 10; ++e) acc[e] += w * edp[e];
        }
        for (int i = 0; i < 11; ++i) {
            red[tid] = acc[i];
            __syncthreads();
            for (int s = 128; s > 0; s >>= 1) {
                if (tid < s) red[tid] += red[tid + s];
                __syncthreads();
            }
            if (tid == 0) {
                if (i == 10) ws[JS_F + j*3 + c] = red[0];
                else         ws[JE_F + (j*3 + c)*10 + i] = red[0];
            }
            __syncthreads();
        }
    }
}

// ---------------- phase 2: batch (256 thr per b) ----------------
__device__ void ph_batch(int b, int t, char* SMEM,
    const float* __restrict__ body, const float* __restrict__ hand,
    const float* __restrict__ head, const float* __restrict__ expr,
    const float* __restrict__ pelvis, const float* __restrict__ hand_mean,
    const float* __restrict__ ws, f16* __restrict__ PFH, f16* __restrict__ AH)
{
    float (*rot)[9] = (float(*)[9])SMEM;
    float (*jnt)[3] = (float(*)[3])(SMEM + 1984);
    f16* AHb = AH + (size_t)b * 1024;
    #pragma unroll
    for (int i = 0; i < 4; ++i) AHb[t + i*256] = (f16)0.f;

    if (t < JN) {
        int j = t;
        float r0, r1, r2;
        if (j == 0) {
            r0 = pelvis[b*3+0]; r1 = pelvis[b*3+1]; r2 = pelvis[b*3+2];
        } else if (j <= 21) {
            int o = b*63 + (j-1)*3;
            r0 = body[o]; r1 = body[o+1]; r2 = body[o+2];
        } else if (j <= 24) {
            int o = b*9 + (j-22)*3;
            r0 = head[o]; r1 = head[o+1]; r2 = head[o+2];
        } else {
            int h = (j-25)*3;
            r0 = hand[b*90+h+0] + hand_mean[h+0];
            r1 = hand[b*90+h+1] + hand_mean[h+1];
            r2 = hand[b*90+h+2] + hand_mean[h+2];
        }
        float a2  = r0*r0 + r1*r1 + r2*r2 + 1e-12f;
        float ang = sqrtf(a2);
        float inv = 1.0f / ang;
        float kx = r0*inv, ky = r1*inv, kz = r2*inv;
        float s = sinf(ang), c = cosf(ang), ic = 1.0f - c;
        rot[j][0] = c + ic*kx*kx;    rot[j][1] = ic*kx*ky - s*kz; rot[j][2] = ic*kx*kz + s*ky;
        rot[j][3] = ic*kx*ky + s*kz; rot[j][4] = c + ic*ky*ky;    rot[j][5] = ic*ky*kz - s*kx;
        rot[j][6] = ic*kx*kz - s*ky; rot[j][7] = ic*ky*kz + s*kx; rot[j][8] = c + ic*kz*kz;
        #pragma unroll
        for (int cc = 0; cc < 3; ++cc) {
            float acc = ws[JS_F + j*3 + cc];
            #pragma unroll
            for (int e = 0; e < 10; ++e)
                acc += expr[b*10 + e] * ws[JE_F + (j*3 + cc)*10 + e];
            jnt[j][cc] = acc;
        }
    }
    __syncthreads();   // rot/jnt ready AND AH zero-init complete (all waves)

    #pragma unroll
    for (int i = 0; i < 2; ++i) {
        int k = t + i*256;
        float val = 0.f;
        if (k < 486) {
            int jj = k/9 + 1, ii = k%9;
            float d = (ii == 0 || ii == 4 || ii == 8) ? 1.0f : 0.0f;
            val = rot[jj][ii] - d;
        } else if (k < 496) {
            val = expr[b*10 + (k-486)];
        }
        PFH[(size_t)((b>>4)*16 + (k>>5))*512 + (((k>>3)&3)*16 + (b&15))*8 + (k&7)] = (f16)val;
    }

    if (t < 64) {      // wave 0: serial chain, shfl only, no barriers
        int r = t >> 2, cc = t & 3;
        float g = 0.f;
        if (t < 12) g = (cc < 3) ? rot[0][r*3 + cc] : jnt[0][r];
        for (int j = 0; j < JN; ++j) {
            if (j > 0) {
                float g0 = __shfl(g, r*4+0), g1 = __shfl(g, r*4+1);
                float g2 = __shfl(g, r*4+2), g3 = __shfl(g, r*4+3);
                if (cc < 3) g = g0*rot[j][cc] + g1*rot[j][3+cc] + g2*rot[j][6+cc];
                else        g = g0*(jnt[j][0]-jnt[j-1][0]) + g1*(jnt[j][1]-jnt[j-1][1])
                              + g2*(jnt[j][2]-jnt[j-1][2]) + g3;
            }
            float h0 = __shfl(g, r*4+0), h1 = __shfl(g, r*4+1), h2 = __shfl(g, r*4+2);
            float aval = g;
            if (cc == 3) aval = g - (h0*jnt[j][0] + h1*jnt[j][1] + h2*jnt[j][2]);
            if (t < 12)
                AHb[(j>>5)*512 + (((j>>3)&3)*16 + t)*8 + (j&7)] = (f16)aval;
        }
    }
    __syncthreads();   // protect rot/jnt LDS before next unit / phase
}

// ---------------- phase 3: pose (unit = 64 cols x 256 batches) -------------
// 4 waves: wm = w>>1 (col-group of 32), wb = w&1 (batch-group of 128).
// acc[2][8] = 64 AGPR. Split-K stage (R7 conflict-free mapping). Direct
// f16x4 VPH2 stores (R3-proven, full-line merged in L2).
__device__ void ph_pose(int unit, int t, char* SMEM,
    const float* __restrict__ pd, const float* __restrict__ ed,
    const float* __restrict__ ws, const f16* __restrict__ PFH,
    f16* __restrict__ VPH2)
{
    f16*   Bt  = (f16*)SMEM;                  // [64][BTS2]
    float* SDl = (float*)(SMEM + 64*BTS2*2);  // [64]
    const int by = (unit >= 492) ? 1 : 0;
    const int bx = unit - by*492;
    const int n0 = bx * 64;
    const int w = t >> 6, lane = t & 63, l = lane & 15, q = lane >> 4;
    const int wm = w >> 1, wb = w & 1;

    __syncthreads();                          // LDS reuse guard across units
    if (t < 64) { int n = n0 + t; SDl[t] = (n < VC3) ? ws[SD_F + n] : 0.f; }

    f32x4 acc[2][8];
    #pragma unroll
    for (int i = 0; i < 2; ++i)
        #pragma unroll
        for (int j = 0; j < 8; ++j) acc[i][j] = (f32x4)0.f;

    const int krow = t & 31, f8 = t >> 5;     // conflict-free stage mapping

    for (int h = 0; h < 2; ++h) {
        if (h) __syncthreads();               // all waves done with Bt half 0
        #pragma unroll
        for (int cs = 0; cs < 2; ++cs) {
            const int c  = cs*32 + f8*4;
            const int nb = n0 + c;
            #pragma unroll 4
            for (int it = 0; it < 8; ++it) {
                int k = h*256 + krow + it*32;
                float4 vv = make_float4(0.f, 0.f, 0.f, 0.f);
                if (k < 486) {
                    if (nb + 3 < VC3) vv = *(const float4*)(pd + (size_t)k*VC3 + nb);
                    else {
                        float* pv = (float*)&vv;
                        for (int e = 0; e < 4; ++e)
                            if (nb + e < VC3) pv[e] = pd[(size_t)k*VC3 + nb + e];
                    }
                } else if (k < 496) {
                    float* pv = (float*)&vv;
                    for (int e = 0; e < 4; ++e)
                        if (nb + e < VC3) pv[e] = ed[(size_t)(nb + e)*10 + (k - 486)];
                }
                int kl = krow + it*32;
                Bt[(c+0)*BTS2 + kl] = (f16)vv.x;
                Bt[(c+1)*BTS2 + kl] = (f16)vv.y;
                Bt[(c+2)*BTS2 + kl] = (f16)vv.z;
                Bt[(c+3)*BTS2 + kl] = (f16)vv.w;
            }
        }
        __syncthreads();
        #pragma unroll
        for (int kc8 = 0; kc8 < 8; ++kc8) {
            int kc = h*8 + kc8;
            f16x8 af0 = *(const f16x8*)&Bt[(wm*32 +      l)*BTS2 + kc8*32 + q*8];
            f16x8 af1 = *(const f16x8*)&Bt[(wm*32 + 16 + l)*BTS2 + kc8*32 + q*8];
            #pragma unroll
            for (int jp = 0; jp < 4; ++jp) {
                int bg = by*16 + wb*8 + jp*2;
                f16x8 b0 = *(const f16x8*)&PFH[(size_t)((bg+0)*16 + kc)*512 + lane*8];
                f16x8 b1 = *(const f16x8*)&PFH[(size_t)((bg+1)*16 + kc)*512 + lane*8];
                acc[0][jp*2+0] = __builtin_amdgcn_mfma_f32_16x16x32_f16(af0, b0, acc[0][jp*2+0], 0, 0, 0);
                acc[1][jp*2+0] = __builtin_amdgcn_mfma_f32_16x16x32_f16(af1, b0, acc[1][jp*2+0], 0, 0, 0);
                acc[0][jp*2+1] = __builtin_amdgcn_mfma_f32_16x16x32_f16(af0, b1, acc[0][jp*2+1], 0, 0, 0);
                acc[1][jp*2+1] = __builtin_amdgcn_mfma_f32_16x16x32_f16(af1, b1, acc[1][jp*2+1], 0, 0, 0);
            }
        }
    }

    // epilogue: lane holds D[c = wm*32+mt*16+q*4+i][b = by*256+wb*128+nt*16+l]
    #pragma unroll
    for (int mt = 0; mt < 2; ++mt) {
        int cb  = wm*32 + mt*16 + q*4;
        int nb2 = n0 + cb;
        #pragma unroll
        for (int nt = 0; nt < 8; ++nt) {
            int b = by*256 + wb*128 + nt*16 + l;
            f16 pack[4];
            #pragma unroll
            for (int i = 0; i < 4; ++i)
                pack[i] = (f16)(acc[mt][nt][i] + SDl[cb + i]);
            *(f16x4*)&VPH2[(size_t)b*NPAD + nb2] = *(f16x4*)&pack[0];
        }
    }
}

// ---------------- phase 4: lbs (unit = 64 verts x 8 batches) ---------------
__device__ void ph_lbs(int unit, int t, char* SMEM,
    const float* __restrict__ gt, const float* __restrict__ ws,
    const f16* __restrict__ AH, const f16* __restrict__ lwT,
    const f16* __restrict__ VPH2, float* __restrict__ out)
{
    f16*   LV   = (f16*)SMEM;               // 1536 halves (3 KB)
    float* OUTS = (float*)(SMEM + 3072);    // 1536 f (6 KB)
    const int vtile = unit % 164;
    const int v0 = vtile * 64;
    const int bbase = (unit / 164) * 8;
    const int w = t >> 6, lane = t & 63, l = lane & 15, q = lane >> 4;

    if (t < 192) {
        int bl = t / 24, c8 = t % 24;
        *(f16x8*)&LV[bl*192 + c8*8] =
            *(const f16x8*)&VPH2[(size_t)(bbase + bl)*NPAD + v0*3 + c8*8];
    }
    __syncthreads();

    f32x4 acc[2][4];
    #pragma unroll
    for (int i = 0; i < 2; ++i)
        #pragma unroll
        for (int j = 0; j < 4; ++j) acc[i][j] = (f32x4)0.f;

    #pragma unroll
    for (int ks = 0; ks < 2; ++ks) {
        f16x8 af[2], bf[4];
        #pragma unroll
        for (int nt = 0; nt < 4; ++nt)
            bf[nt] = *(const f16x8*)&lwT[(size_t)(vtile*4 + nt)*1024 + ks*512 + lane*8];
        #pragma unroll
        for (int mt = 0; mt < 2; ++mt)
            af[mt] = *(const f16x8*)&AH[(size_t)(bbase + w*2 + mt)*1024 + ks*512 + lane*8];
        #pragma unroll
        for (int mt = 0; mt < 2; ++mt)
            #pragma unroll
            for (int nt = 0; nt < 4; ++nt)
                acc[mt][nt] = __builtin_amdgcn_mfma_f32_16x16x32_f16(af[mt], bf[nt], acc[mt][nt], 0, 0, 0);
    }

    float yoff = ws[Y_F];
    #pragma unroll
    for (int mt = 0; mt < 2; ++mt) {
        int bl = w*2 + mt;
        float add = 0.f;
        if (q < 3) add = gt[(bbase + bl)*3 + q] + (q == 1 ? yoff : 0.f);
        const f16* vrow = &LV[bl*192];
        #pragma unroll
        for (int nt = 0; nt < 4; ++nt) {
            if (q < 3) {
                int o = (nt*16 + l)*3;
                float vx = (float)vrow[o], vy = (float)vrow[o+1], vz = (float)vrow[o+2];
                f32x4 T = acc[mt][nt];
                OUTS[bl*192 + o + q] = T[0]*vx + T[1]*vy + T[2]*vz + T[3] + add;
            }
        }
    }
    __syncthreads();
    #pragma unroll
    for (int pass = 0; pass < 6; ++pass) {
        int idx = pass*256 + t;
        int bl  = idx / 192;
        int c   = idx - bl*192;
        if (v0*3 + c < VC3)
            out[(size_t)(bbase + bl)*VC3 + v0*3 + c] = OUTS[idx];
    }
}

// ---------------- the single persistent kernel ----------------
__global__ __launch_bounds__(256, 3) void k_all(
    const float* vt, const float* shapedirs, const float* shape,
    const float* lw, const float* jr, const float* exprdirs,
    const float* pd, const float* body, const float* hand, const float* head,
    const float* expr, const float* pelvis, const float* hand_mean,
    const float* gt, float* ws, f16* lwT, f16* PFH, f16* AH, f16* VPH2,
    float* out, unsigned* bar)
{
    __shared__ __align__(16) char SMEM[SMEM_BYTES];
    const int t  = threadIdx.x;
    const unsigned nb = gridDim.x;
    unsigned* cnt = bar;
    unsigned* gen = bar + 1;

    for (int u = blockIdx.x; u < NB_PREP; u += nb)
        ph_prep(u, t, SMEM, vt, shapedirs, shape, lw, jr, exprdirs, ws, lwT);
    gsync(cnt, gen, nb, t);

    for (int u = blockIdx.x; u < BN; u += nb)
        ph_batch(u, t, SMEM, body, hand, head, expr, pelvis, hand_mean, ws, PFH, AH);
    gsync(cnt, gen, nb, t);

    for (int u = blockIdx.x; u < NB_POSE; u += nb)
        ph_pose(u, t, SMEM, pd, exprdirs, ws, PFH, VPH2);
    gsync(cnt, gen, nb, t);

    for (int u = blockIdx.x; u < NB_LBS; u += nb)
        ph_lbs(u, t, SMEM, gt, ws, AH, lwT, VPH2, out);
}

extern "C" void kernel_launch(void* const* d_in, const int* in_sizes, int n_in,
                              void* d_out, int out_size, void* d_ws, size_t ws_size,
                              hipStream_t stream)
{
    const float* shape  = (const float*)d_in[0];
    const float* body   = (const float*)d_in[1];
    const float* hand   = (const float*)d_in[2];
    const float* head   = (const float*)d_in[3];
    const float* expr   = (const float*)d_in[4];
    const float* pelvis = (const float*)d_in[5];
    const float* gtrans = (const float*)d_in[6];
    const float* vt     = (const float*)d_in[7];
    const float* shdirs = (const float*)d_in[8];
    const float* exdirs = (const float*)d_in[9];
    const float* pdirs  = (const float*)d_in[10];
    const float* lbsw   = (const float*)d_in[11];
    const float* jreg   = (const float*)d_in[12];
    const float* hmean  = (const float*)d_in[13];
    float*    wsf = (float*)d_ws;
    f16*      PFH  = (f16*)((char*)d_ws + PFH_BYTE);
    f16*      AH   = (f16*)((char*)d_ws + AH_BYTE);
    f16*      VPH2 = (f16*)((char*)d_ws + VPH_BYTE);
    f16*      lwT  = (f16*)((char*)d_ws + LWT_BYTE);
    unsigned* bar  = (unsigned*)((char*)d_ws + BAR_BYTE);
    float*    out  = (float*)d_out;

    hipMemsetAsync(bar, 0, 8, stream);
    hipLaunchKernelGGL(k_all, dim3(GRID), dim3(256), 0, stream,
                       vt, shdirs, shape, lbsw, jreg, exdirs, pdirs,
                       body, hand, head, expr, pelvis, hmean, gtrans,
                       wsf, lwT, PFH, AH, VPH2, out, bar);
}